// Round 6
// baseline (157.810 us; speedup 1.0000x reference)
//
#include <hip/hip_runtime.h>
#include <math.h>

#define ALPHA   0.99f
#define ONE_M   0.01f     // 1 - ALPHA
#define T_LEN   4000
#define F_DIM   64
#define NCHUNK  50
#define CHUNK_L 80        // T_LEN / NCHUNK
#define NG      16        // float4 groups per row = F_DIM/4 (full 256B rows)
#define NTHREADS (NCHUNK * NG)   // 800
#define PF      4         // float4 loads per group (1 KB span per thread)
#define NGRP    (CHUNK_L / PF)   // 20 groups

typedef float f32x4 __attribute__((ext_vector_type(4)));

// Volatile asm loads: hipcc cannot sink/merge these. One group = 4 x
// global_load_dwordx4 from a single base with 256B immediate offsets.
#define GLD_GROUP(B, P)                                                     \
  asm volatile("global_load_dwordx4 %0, %4, off\n\t"                        \
               "global_load_dwordx4 %1, %4, off offset:256\n\t"             \
               "global_load_dwordx4 %2, %4, off offset:512\n\t"             \
               "global_load_dwordx4 %3, %4, off offset:768"                 \
               : "=&v"((B)[0]), "=&v"((B)[1]), "=&v"((B)[2]), "=&v"((B)[3]) \
               : "v"(P) : "memory")

#define WAITV(n)                                                            \
  do { asm volatile("s_waitcnt vmcnt(" #n ")" ::: "memory");                \
       __builtin_amdgcn_sched_barrier(0); } while (0)

// Exact chunked scan, per (b, f):
//   mu_L  = a^L mu_0 + m_L                     (m: EMA of x within chunk)
//   var_L = a^L var_0 + SP + c2*SU*mu_0 + R*mu_0^2
//   SP = EMA of u^2, SU = sum of u (u = x - m), c2 = -2(1-a)a^L, R = a^{L+1}(1-a^L)
//
// Depth-4 rotating buffer: 3 groups of loads always in flight, drained with
// counted vmcnt (pass-2 counts include the 4 stores/group in the queue).
__global__ __launch_bounds__(NTHREADS, 2)
void erbnorm_kernel(const float* __restrict__ x, float* __restrict__ out, float aL) {
    const int b   = blockIdx.x;
    const int tid = threadIdx.x;
    const int c   = tid >> 4;          // chunk 0..49
    const int g   = tid & 15;          // float4 group 0..15

    __shared__ float s_m [NCHUNK][F_DIM];   // m  -> entering mu (after combine)
    __shared__ float s_sp[NCHUNK][F_DIM];   // SP -> entering var
    __shared__ float s_su[NCHUNK][F_DIM];   // SU

    const size_t base = ((size_t)b * T_LEN + (size_t)c * CHUNK_L) * F_DIM + g * 4;
    const float* xp = x + base;

    // ---- pass 1: per-chunk transition coefficients (4 features/thread) ----
    {
        f32x4 m = 0.f, sp = 0.f, su = 0.f;
        f32x4 v4[4][PF];
        GLD_GROUP(v4[0], xp + (size_t)0 * PF * F_DIM);
        GLD_GROUP(v4[1], xp + (size_t)1 * PF * F_DIM);
        GLD_GROUP(v4[2], xp + (size_t)2 * PF * F_DIM);
#pragma unroll
        for (int gg = 0; gg < NGRP; ++gg) {
            if (gg + 3 < NGRP)
                GLD_GROUP(v4[(gg + 3) & 3], xp + (size_t)(gg + 3) * PF * F_DIM);
            if      (gg <  NGRP - 3) WAITV(12);
            else if (gg == NGRP - 3) WAITV(8);
            else if (gg == NGRP - 2) WAITV(4);
            else                     WAITV(0);
#pragma unroll
            for (int j = 0; j < PF; ++j) {
                f32x4 xi = v4[gg & 3][j];
                m = ALPHA * m + ONE_M * xi;
                f32x4 u = xi - m;
                sp = ALPHA * sp + ONE_M * (u * u);
                su = su + u;
            }
        }
        *(f32x4*)&s_m [c][g * 4] = m;
        *(f32x4*)&s_sp[c][g * 4] = sp;
        *(f32x4*)&s_su[c][g * 4] = su;
    }
    __syncthreads();

    // ---- combine: serial chain over 50 chunks, one thread per feature ----
    if (tid < F_DIM) {
        const float step = -30.f / 63.f;
        float mu  = -60.f + (float)tid * step;
        float var = 1600.f;
        const float R  = ALPHA * aL * (1.f - aL);   // a^(L+1)(1-a^L)
        const float c2 = -2.f * ONE_M * aL;         // -2(1-a)a^L
        for (int cc = 0; cc < NCHUNK; ++cc) {
            float m  = s_m [cc][tid];
            float sp = s_sp[cc][tid];
            float su = s_su[cc][tid];
            s_m [cc][tid] = mu;                     // entering state for pass 2
            s_sp[cc][tid] = var;
            float mu_n = aL * mu + m;
            var = aL * var + sp + (c2 * su) * mu + R * mu * mu;
            mu = mu_n;
        }
    }
    __syncthreads();

    // ---- pass 2: replay with exact entering state, emit outputs ----
    {
        f32x4 mu  = *(const f32x4*)&s_m [c][g * 4];
        f32x4 var = *(const f32x4*)&s_sp[c][g * 4];
        float* op = out + base;
        f32x4 v4[4][PF];
        GLD_GROUP(v4[0], xp + (size_t)0 * PF * F_DIM);
        GLD_GROUP(v4[1], xp + (size_t)1 * PF * F_DIM);
        GLD_GROUP(v4[2], xp + (size_t)2 * PF * F_DIM);
#pragma unroll
        for (int gg = 0; gg < NGRP; ++gg) {
            if (gg + 3 < NGRP)
                GLD_GROUP(v4[(gg + 3) & 3], xp + (size_t)(gg + 3) * PF * F_DIM);
            // Counted drains; queue holds loads AND this pass's 4 stores/group.
            if      (gg == 0)        WAITV(12);
            else if (gg == 1)        WAITV(16);
            else if (gg == 2)        WAITV(20);
            else if (gg <  NGRP - 3) WAITV(24);
            else if (gg == NGRP - 3) WAITV(20);
            else if (gg == NGRP - 2) WAITV(16);
            else                     WAITV(12);
#pragma unroll
            for (int j = 0; j < PF; ++j) {
                f32x4 xi = v4[gg & 3][j];
                mu = ALPHA * mu + ONE_M * xi;
                f32x4 d = xi - mu;
                var = ALPHA * var + ONE_M * (d * d);
                f32x4 o;
                o[0] = d[0] * __builtin_amdgcn_rsqf(var[0]);
                o[1] = d[1] * __builtin_amdgcn_rsqf(var[1]);
                o[2] = d[2] * __builtin_amdgcn_rsqf(var[2]);
                o[3] = d[3] * __builtin_amdgcn_rsqf(var[3]);
                *(f32x4*)(op + (size_t)(gg * PF + j) * F_DIM) = o;
            }
        }
    }
}

extern "C" void kernel_launch(void* const* d_in, const int* in_sizes, int n_in,
                              void* d_out, int out_size, void* d_ws, size_t ws_size,
                              hipStream_t stream) {
    const float* x = (const float*)d_in[0];
    float* out = (float*)d_out;
    const float aL = (float)pow(0.99, (double)CHUNK_L);  // a^L
    hipLaunchKernelGGL(erbnorm_kernel, dim3(256), dim3(NTHREADS), 0, stream,
                       x, out, aL);
}